// Round 17
// baseline (230.936 us; speedup 1.0000x reference)
//
#include <hip/hip_runtime.h>

#define D 128
#define BP_LOG 7           // partition bucket = 128 rows (nb=782: long runs)
#define ROWS_H 64          // sortspmm half-bucket = 64 rows
#define MAX_NB 1024        // partition buckets; supports N <= 131072
#define CHUNK_LOG 12       // partition chunk = 4096 edges
#define CAP 2560           // LDS record capacity per half (mean 2047, +11 sigma)

typedef short bf16x8 __attribute__((ext_vector_type(8)));
typedef float f32x4  __attribute__((ext_vector_type(4)));

// round-to-nearest-even float -> bf16 bits
static __device__ __forceinline__ unsigned short f2bf(float f) {
    unsigned u = __float_as_uint(f);
    u += 0x7FFFu + ((u >> 16) & 1u);
    return (unsigned short)(u >> 16);
}

// ---------------------------------------------------------------------------
// Wt[mat][n][k] = bf16(Wmat[k][n]); also zeroes bhist (folds the memset).
// ---------------------------------------------------------------------------
__global__ __launch_bounds__(256) void wconv_kernel(
    const float* __restrict__ W, const float* __restrict__ Ws,
    short* __restrict__ Wt, int* __restrict__ bhist, int nb)
{
    const int idx = blockIdx.x * 256 + threadIdx.x;
    if (idx < 2 * D * D) {
        const int mat = idx >> 14;
        const int rem = idx & (D * D - 1);
        const int n = rem >> 7, k = rem & (D - 1);
        const float* src = mat ? Ws : W;
        Wt[idx] = (short)f2bf(src[k * D + n]);
    }
    if (idx < nb) bhist[idx] = 0;
}

// ---------------------------------------------------------------------------
// Bucket histogram over 128-row buckets. int4-vectorized reads (G13).
// ---------------------------------------------------------------------------
__global__ __launch_bounds__(256) void bhist_kernel(
    const int* __restrict__ rows, int* __restrict__ bhist, int E, int nb)
{
    __shared__ int h[MAX_NB];
    const int t = threadIdx.x;
    for (int i = t; i < nb; i += 256) h[i] = 0;
    __syncthreads();

    const int nq = E >> 2;              // int4 quads
    int i = blockIdx.x * 256 + t;
    const int stride = gridDim.x * 256;
    for (; i < nq; i += stride) {
        const int4 r4 = ((const int4*)rows)[i];
        atomicAdd(&h[r4.x >> BP_LOG], 1);
        atomicAdd(&h[r4.y >> BP_LOG], 1);
        atomicAdd(&h[r4.z >> BP_LOG], 1);
        atomicAdd(&h[r4.w >> BP_LOG], 1);
    }
    // tail
    for (int e = (nq << 2) + blockIdx.x * 256 + t; e < E; e += stride)
        atomicAdd(&h[rows[e] >> BP_LOG], 1);
    __syncthreads();

    for (int i2 = t; i2 < nb; i2 += 256) {
        const int c = h[i2];
        if (c) atomicAdd(&bhist[i2], c);
    }
}

// ---------------------------------------------------------------------------
// Exclusive scan over nb bucket counts -> bptr[0..nb], bcur copy.
// ---------------------------------------------------------------------------
__global__ __launch_bounds__(256) void bscan_kernel(
    const int* __restrict__ bhist, int* __restrict__ bptr,
    int* __restrict__ bcur, int nb)
{
    const int t = threadIdx.x;
    const int base_i = t * 4;
    int v[4];
    int s = 0;
#pragma unroll
    for (int k = 0; k < 4; ++k) {
        v[k] = (base_i + k < nb) ? bhist[base_i + k] : 0;
        s += v[k];
    }

    const int lane = t & 63, wv = t >> 6;
    int sc = s;
    for (int o = 1; o < 64; o <<= 1) {
        const int u = __shfl_up(sc, o, 64);
        if (lane >= o) sc += u;
    }
    __shared__ int wsum[4];
    if (lane == 63) wsum[wv] = sc;
    __syncthreads();

    int wbase = 0;
    for (int w2 = 0; w2 < wv; ++w2) wbase += wsum[w2];
    int excl = wbase + (sc - s);
#pragma unroll
    for (int k = 0; k < 4; ++k) {
        if (base_i + k < nb) { bptr[base_i + k] = excl; bcur[base_i + k] = excl; }
        excl += v[k];
    }
    if (t == 255) bptr[nb] = wsum[0] + wsum[1] + wsum[2] + wsum[3];  // == E
}

// ---------------------------------------------------------------------------
// Fused: blocks [0, part_grid) = edge partition (FIRST in grid -> resident
// from t=0, hides under the GEMM); blocks [part_grid, part_grid+ntiles) =
// MFMA dual GEMM, ONE 64-row tile per block (2x block parallelism for the
// latency-bound gemm; r13 showed 17% occupancy at 2 tiles/block).
// GEMM: waves 0-1: s1b = bf16(x@W); waves 2-3: skipb = bf16(x@Ws + b).
// Partition: 4096-edge chunks into 128-row buckets (5.2-edge runs).
// Record: ((row & 127) << 20) | col, weight bits.
// ---------------------------------------------------------------------------
__global__ __launch_bounds__(256) void gemm_part_kernel(
    const float* __restrict__ x, const short* __restrict__ Wt,
    const float* __restrict__ b, unsigned short* __restrict__ s1b,
    unsigned short* __restrict__ skipb, int N,
    const int* __restrict__ rows, const int* __restrict__ cols,
    const float* __restrict__ ew, int* __restrict__ bcur,
    int2* __restrict__ se1, int E, int nb, int part_grid)
{
    __shared__ short sx[64 * D];   // 16 KiB; partition branch aliases as int[]

    const int t = threadIdx.x;

    if (blockIdx.x < part_grid) {
        // ---------------- partition branch ----------------
        int* h = (int*)sx;
        const int nchunks = (E + (1 << CHUNK_LOG) - 1) >> CHUNK_LOG;

        for (int c = blockIdx.x; c < nchunks; c += part_grid) {
            const int ebeg = c << CHUNK_LOG;
            const int eend = min(ebeg + (1 << CHUNK_LOG), E);

            for (int i = t; i < nb; i += 256) h[i] = 0;
            __syncthreads();

            for (int e = ebeg + t; e < eend; e += 256)
                atomicAdd(&h[rows[e] >> BP_LOG], 1);
            __syncthreads();

            for (int i = t; i < nb; i += 256) {
                const int cnt = h[i];
                h[i] = cnt ? atomicAdd(&bcur[i], cnt) : 0;
            }
            __syncthreads();

            for (int e = ebeg + t; e < eend; e += 256) {
                const int r    = rows[e];
                const int bkt  = r >> BP_LOG;
                const int slot = atomicAdd(&h[bkt], 1);
                se1[slot] = make_int2(((r & 127) << 20) | cols[e],
                                      __float_as_int(ew[e]));
            }
            __syncthreads();
        }
        return;
    }

    // ---------------- MFMA dual GEMM branch (one tile per block) ----------
    const int lane = t & 63;
    const int w    = t >> 6;

    const int bmat = w >> 1;
    const int bn0  = (w & 1) * 64 + (lane & 15);
    const int bk0  = (lane >> 4) * 8;
    bf16x8 Bf[4][4];   // [nf][ks]
#pragma unroll
    for (int nf = 0; nf < 4; ++nf)
#pragma unroll
        for (int ks = 0; ks < 4; ++ks)
            Bf[nf][ks] = *(const bf16x8*)&Wt[
                ((size_t)bmat * D + bn0 + nf * 16) * D + ks * 32 + bk0];

    float bias[4];
#pragma unroll
    for (int nf = 0; nf < 4; ++nf)
        bias[nf] = (w >= 2) ? b[(w - 2) * 64 + nf * 16 + (lane & 15)] : 0.f;

    const int rt = blockIdx.x - part_grid;   // one tile per block
    const int r0 = rt << 6;
    const int trow = t >> 2;
    const int tk   = (t & 3) * 4;

    {
        const int grow = min(r0 + trow, N - 1);
        const float* xrow = &x[(size_t)grow * D];
#pragma unroll
        for (int i = 0; i < 8; ++i) {
            const int k = tk + i * 16;
            const float4 v = *(const float4*)&xrow[k];
            const unsigned lo = (unsigned)f2bf(v.x) | ((unsigned)f2bf(v.y) << 16);
            const unsigned hi = (unsigned)f2bf(v.z) | ((unsigned)f2bf(v.w) << 16);
            unsigned byte = trow * 256 + k * 2;
            byte ^= (unsigned)((trow & 7) << 4);
            *(uint2*)((char*)sx + byte) = make_uint2(lo, hi);
        }
        __syncthreads();

        f32x4 acc[4][4];
#pragma unroll
        for (int mf = 0; mf < 4; ++mf)
#pragma unroll
            for (int nf = 0; nf < 4; ++nf)
                acc[mf][nf] = (f32x4){0.f, 0.f, 0.f, 0.f};

#pragma unroll
        for (int ks = 0; ks < 4; ++ks) {
            bf16x8 Af[4];
#pragma unroll
            for (int mf = 0; mf < 4; ++mf) {
                const int row = mf * 16 + (lane & 15);
                unsigned byte = row * 256 + (ks * 32 + bk0) * 2;
                byte ^= (unsigned)((row & 7) << 4);
                Af[mf] = *(const bf16x8*)((const char*)sx + byte);
            }
#pragma unroll
            for (int mf = 0; mf < 4; ++mf)
#pragma unroll
                for (int nf = 0; nf < 4; ++nf)
                    acc[mf][nf] = __builtin_amdgcn_mfma_f32_16x16x32_bf16(
                        Af[mf], Bf[nf][ks], acc[mf][nf], 0, 0, 0);
        }

#pragma unroll
        for (int mf = 0; mf < 4; ++mf) {
#pragma unroll
            for (int i = 0; i < 4; ++i) {
                const int row = r0 + mf * 16 + (lane >> 4) * 4 + i;
                if (row < N) {
                    if (w < 2) {
#pragma unroll
                        for (int nf = 0; nf < 4; ++nf) {
                            const int col = w * 64 + nf * 16 + (lane & 15);
                            s1b[(size_t)row * D + col] = f2bf(acc[mf][nf][i]);
                        }
                    } else {
#pragma unroll
                        for (int nf = 0; nf < 4; ++nf) {
                            const int col = (w - 2) * 64 + nf * 16 + (lane & 15);
                            skipb[(size_t)row * D + col] =
                                f2bf(acc[mf][nf][i] + bias[nf]);
                        }
                    }
                }
            }
        }
    }
}

// ---------------------------------------------------------------------------
// Fused sort + SpMM, single global scan + 16-deep gather MLP.
// Block (512 thr) = one 64-row half of a 128-row partition bucket.
// Staging: ballot-aggregated append of this half's records into LDS, then
// LDS-local count -> wave-0 shuffle scan -> 16-bit permutation.
// Gather: wave wv owns rows [wv*8, wv*8+8): 16-deep (then 8, then serial)
// edge reads via recs[perm[p]], coalesced s1b gathers,
// out[r] = agg + skipb[r] (pure write).
// Overflow (> CAP): in-block filtered atomic fallback.
// ---------------------------------------------------------------------------
__global__ __launch_bounds__(512) void sortspmm_kernel(
    const unsigned short* __restrict__ s1b,
    const unsigned short* __restrict__ skipb,
    const int* __restrict__ bptr, const int2* __restrict__ se1,
    float* __restrict__ out, int N)
{
    __shared__ long long recs[CAP];          // 20 KiB, append order
    __shared__ unsigned short perm[CAP];     // 5 KiB, row-sorted -> append idx
    __shared__ int rpos[ROWS_H];             // row start
    __shared__ int rcur[ROWS_H];             // counter / cursor (final = end)
    __shared__ int nstage;

    const int t    = threadIdx.x;
    const int lane = t & 63;
    const int wv   = t >> 6;            // 0..7
    const int sb   = blockIdx.x >> 1;   // super-bucket
    const int hh   = blockIdx.x & 1;    // half
    const int r0   = (sb << BP_LOG) + (hh << 6);
    const int j    = lane * 2;

    const int beg  = bptr[sb];
    const int end  = bptr[sb + 1];
    const long long* seq = (const long long*)se1;

    if (t < ROWS_H) rcur[t] = 0;
    if (t == 0) nstage = 0;
    __syncthreads();

    // single scan: stage this half's records (unsorted, wave-aggregated)
    for (int e = beg + t; e < end; e += 512) {
        const long long rec = seq[e];
        const int rl = (int)((unsigned)rec >> 20);
        const bool m = ((rl >> 6) == hh);
        const unsigned long long bal = __ballot(m);
        if (bal) {
            const int leader = (int)__ffsll((long long)bal) - 1;
            int base = 0;
            if (lane == leader) base = atomicAdd(&nstage, __popcll(bal));
            base = __shfl(base, leader, 64);
            if (m) {
                const int slot = base +
                    (int)__popcll(bal & ((1ull << lane) - 1ull));
                if (slot < CAP) recs[slot] = rec;
            }
        }
    }
    __syncthreads();
    const int hcnt = nstage;

    if (hcnt <= CAP) {
        // LDS-local: count rows
        for (int i = t; i < hcnt; i += 512)
            atomicAdd(&rcur[(int)((unsigned)recs[i] >> 20) & 63], 1);
        __syncthreads();

        // wave-0 shuffle scan over the 64 counts -> exclusive starts
        if (t < ROWS_H) {
            const int v = rcur[t];
            int sc = v;
#pragma unroll
            for (int o = 1; o < 64; o <<= 1) {
                const int u = __shfl_up(sc, o, 64);
                if (lane >= o) sc += u;
            }
            rpos[t] = sc - v;
            rcur[t] = sc - v;
        }
        __syncthreads();

        // LDS-local: build 16-bit permutation (row-sorted -> append index)
        for (int i = t; i < hcnt; i += 512) {
            const int rl = (int)((unsigned)recs[i] >> 20) & 63;
            perm[atomicAdd(&rcur[rl], 1)] = (unsigned short)i;
        }
        __syncthreads();

        // gather: wave per row (8 rows per wave), 16-deep MLP
        for (int i2 = 0; i2 < 8; ++i2) {
            const int rr = wv * 8 + i2;
            const int r  = r0 + rr;
            if (r >= N) break;
            int p        = rpos[rr];
            const int pe = rcur[rr];    // final cursor == row end

            float2 acc = make_float2(0.f, 0.f);
            for (; p + 16 <= pe; p += 16) {
                int idx[16];
#pragma unroll
                for (int k = 0; k < 16; ++k) idx[k] = perm[p + k];
                long long ed[16];
#pragma unroll
                for (int k = 0; k < 16; ++k) ed[k] = recs[idx[k]];
                unsigned pk[16];
#pragma unroll
                for (int k = 0; k < 16; ++k)
                    pk[k] = *(const unsigned*)&s1b[
                        (size_t)((unsigned)ed[k] & 0xFFFFFu) * D + j];
#pragma unroll
                for (int k = 0; k < 16; ++k) {
                    const float w = __int_as_float((int)(ed[k] >> 32));
                    acc.x = fmaf(w, __uint_as_float(pk[k] << 16), acc.x);
                    acc.y = fmaf(w, __uint_as_float(pk[k] & 0xFFFF0000u), acc.y);
                }
            }
            for (; p + 8 <= pe; p += 8) {
                int idx[8];
#pragma unroll
                for (int k = 0; k < 8; ++k) idx[k] = perm[p + k];
                long long ed[8];
#pragma unroll
                for (int k = 0; k < 8; ++k) ed[k] = recs[idx[k]];
                unsigned pk[8];
#pragma unroll
                for (int k = 0; k < 8; ++k)
                    pk[k] = *(const unsigned*)&s1b[
                        (size_t)((unsigned)ed[k] & 0xFFFFFu) * D + j];
#pragma unroll
                for (int k = 0; k < 8; ++k) {
                    const float w = __int_as_float((int)(ed[k] >> 32));
                    acc.x = fmaf(w, __uint_as_float(pk[k] << 16), acc.x);
                    acc.y = fmaf(w, __uint_as_float(pk[k] & 0xFFFF0000u), acc.y);
                }
            }
            for (; p < pe; ++p) {
                const long long ed = recs[perm[p]];
                const unsigned pk = *(const unsigned*)&s1b[
                    (size_t)((unsigned)ed & 0xFFFFFu) * D + j];
                const float w = __int_as_float((int)(ed >> 32));
                acc.x = fmaf(w, __uint_as_float(pk << 16), acc.x);
                acc.y = fmaf(w, __uint_as_float(pk & 0xFFFF0000u), acc.y);
            }

            const unsigned sk = *(const unsigned*)&skipb[(size_t)r * D + j];
            float2 o;
            o.x = acc.x + __uint_as_float(sk << 16);
            o.y = acc.y + __uint_as_float(sk & 0xFFFF0000u);
            *(float2*)&out[(size_t)r * D + j] = o;
        }
    } else {
        // overflow fallback: init rows with skip, then filtered atomics
        const int nr = min(ROWS_H, N - r0);
        for (int idx = t; idx < nr * 64; idx += 512) {
            const int rr = idx >> 6;
            const int cc = (idx & 63) * 2;
            const unsigned sk = *(const unsigned*)&skipb[(size_t)(r0 + rr) * D + cc];
            *(float2*)&out[(size_t)(r0 + rr) * D + cc] =
                make_float2(__uint_as_float(sk << 16),
                            __uint_as_float(sk & 0xFFFF0000u));
        }
        __syncthreads();

        for (int e = beg + wv; e < end; e += 8) {
            const long long ed = seq[e];
            const unsigned key = (unsigned)ed;
            const int rl = (int)(key >> 20);
            if ((rl >> 6) != hh) continue;
            const float w = __int_as_float((int)(ed >> 32));
            const unsigned pk = *(const unsigned*)&s1b[
                (size_t)(key & 0xFFFFFu) * D + j];
            float* op = &out[(size_t)(r0 + (rl & 63)) * D + j];
            unsafeAtomicAdd(op,     w * __uint_as_float(pk << 16));
            unsafeAtomicAdd(op + 1, w * __uint_as_float(pk & 0xFFFF0000u));
        }
    }
}

// ---------------------------------------------------------------------------
// Fallback vector dual GEMM (ws too small): fp32 math, bf16 s1 store,
// fp32 out init (used with the atomic spmm_edges fallback).
// ---------------------------------------------------------------------------
__global__ __launch_bounds__(512) void dual_gemm_fb_kernel(
    const float* __restrict__ x, const float* __restrict__ W,
    const float* __restrict__ Ws, const float* __restrict__ b,
    unsigned short* __restrict__ s1b, float* __restrict__ out, int N)
{
    __shared__ float sW[D * D];
    __shared__ float sWs[D * D];

    const int t = threadIdx.x;
    for (int i = t * 4; i < D * D; i += 512 * 4) {
        *(float4*)&sW[i]  = *(const float4*)&W[i];
        *(float4*)&sWs[i] = *(const float4*)&Ws[i];
    }
    __syncthreads();

    const int lane   = t & 63;
    const int wave   = blockIdx.x * 8 + (t >> 6);
    const int nwaves = gridDim.x * 8;
    const int j      = lane * 2;
    const float2 bb  = *(const float2*)&b[j];

    for (int r0 = wave * 4; r0 < N; r0 += nwaves * 4) {
        float2 xr[4];
#pragma unroll
        for (int r = 0; r < 4; ++r)
            xr[r] = *(const float2*)&x[(size_t)(r0 + r) * D + j];

        float2 a1[4], a2[4];
#pragma unroll
        for (int r = 0; r < 4; ++r) {
            a1[r] = make_float2(0.f, 0.f);
            a2[r] = make_float2(0.f, 0.f);
        }

#pragma unroll 8
        for (int k = 0; k < D; ++k) {
            const float2 wk  = *(const float2*)&sW[k * D + j];
            const float2 wsk = *(const float2*)&sWs[k * D + j];
#pragma unroll
            for (int r = 0; r < 4; ++r) {
                const float xv = __shfl((k & 1) ? xr[r].y : xr[r].x, k >> 1, 64);
                a1[r].x = fmaf(xv, wk.x,  a1[r].x);
                a1[r].y = fmaf(xv, wk.y,  a1[r].y);
                a2[r].x = fmaf(xv, wsk.x, a2[r].x);
                a2[r].y = fmaf(xv, wsk.y, a2[r].y);
            }
        }

#pragma unroll
        for (int r = 0; r < 4; ++r) {
            const unsigned pk = (unsigned)f2bf(a1[r].x) |
                                ((unsigned)f2bf(a1[r].y) << 16);
            *(unsigned*)&s1b[(size_t)(r0 + r) * D + j] = pk;
            *(float2*)&out[(size_t)(r0 + r) * D + j] =
                make_float2(a2[r].x + bb.x, a2[r].y + bb.y);
        }
    }
}

// ---------------------------------------------------------------------------
// Fallback: edge-parallel atomic scatter (bf16 s1).
// ---------------------------------------------------------------------------
__global__ __launch_bounds__(256) void spmm_edges_kernel(
    const unsigned short* __restrict__ s1b, const int* __restrict__ rows,
    const int* __restrict__ cols, const float* __restrict__ ew,
    float* __restrict__ out, int E)
{
    const int lane = threadIdx.x & 63;
    const int wave = blockIdx.x * (blockDim.x >> 6) + (threadIdx.x >> 6);
    const int nw   = gridDim.x * (blockDim.x >> 6);
    const int j    = lane * 2;

    const int epw   = (E + nw - 1) / nw;
    const int e_beg = wave * epw;
    const int e_end = min(e_beg + epw, E);

    for (int e = e_beg; e < e_end; ++e) {
        const int   r = rows[e];
        const int   c = cols[e];
        const float w = ew[e];
        const unsigned p = *(const unsigned*)&s1b[(size_t)c * D + j];
        float* o = &out[(size_t)r * D + j];
        unsafeAtomicAdd(o,     w * __uint_as_float(p << 16));
        unsafeAtomicAdd(o + 1, w * __uint_as_float(p & 0xFFFF0000u));
    }
}

// ---------------------------------------------------------------------------
extern "C" void kernel_launch(void* const* d_in, const int* in_sizes, int n_in,
                              void* d_out, int out_size, void* d_ws, size_t ws_size,
                              hipStream_t stream) {
    const float* x    = (const float*)d_in[0];
    const int*   rows = (const int*)  d_in[1];
    const int*   cols = (const int*)  d_in[2];
    const float* ew   = (const float*)d_in[3];
    const float* W    = (const float*)d_in[4];
    const float* Ws   = (const float*)d_in[5];
    const float* b    = (const float*)d_in[6];
    float*       out  = (float*)d_out;

    const int N  = in_sizes[0] / D;
    const int E  = in_sizes[1];
    const int nb = (N + 127) >> BP_LOG;   // 128-row partition buckets

    // Workspace: s1b (N*D bf16) | skipb (N*D bf16) | Wt (2*D*D bf16) |
    //            bhist nb | bptr nb+1 | bcur nb | pad | se1 E int2
    const size_t s1_bytes   = ((size_t)N * D * 2 + 15) & ~(size_t)15;
    const size_t skip_bytes = s1_bytes;
    const size_t wt_bytes   = (size_t)2 * D * D * 2;
    const size_t int_bytes  = (((size_t)(3 * nb + 1)) * 4 + 7) & ~(size_t)7;
    const size_t need       = s1_bytes + skip_bytes + wt_bytes + int_bytes
                              + (size_t)E * 8;

    unsigned short* s1b = (unsigned short*)d_ws;

    if (ws_size >= need && nb <= MAX_NB) {
        unsigned short* skipb = (unsigned short*)((char*)d_ws + s1_bytes);
        short* Wt    = (short*)((char*)d_ws + s1_bytes + skip_bytes);
        int*   ibase = (int*)((char*)d_ws + s1_bytes + skip_bytes + wt_bytes);
        int*  bhist  = ibase;                       // nb
        int*  bptr   = ibase + nb;                  // nb+1
        int*  bcur   = ibase + 2 * nb + 1;          // nb
        int2* se1    = (int2*)((char*)d_ws + s1_bytes + skip_bytes + wt_bytes
                               + int_bytes);

        wconv_kernel<<<(2 * D * D + 255) / 256, 256, 0, stream>>>(W, Ws, Wt, bhist, nb);
        bhist_kernel<<<512, 256, 0, stream>>>(rows, bhist, E, nb);
        bscan_kernel<<<1, 256, 0, stream>>>(bhist, bptr, bcur, nb);

        const int nchunks   = (E + (1 << CHUNK_LOG) - 1) >> CHUNK_LOG;
        const int part_grid = min(nchunks, 1024);
        const int ntiles    = (N + 63) >> 6;
        gemm_part_kernel<<<part_grid + ntiles, 256, 0, stream>>>(
            x, Wt, b, s1b, skipb, N, rows, cols, ew, bcur, se1, E, nb, part_grid);

        sortspmm_kernel<<<nb * 2, 512, 0, stream>>>(s1b, skipb, bptr, se1, out, N);
    } else {
        dual_gemm_fb_kernel<<<768, 512, 0, stream>>>(x, W, Ws, b, s1b, (float*)d_out, N);
        spmm_edges_kernel<<<2048, 256, 0, stream>>>(s1b, rows, cols, ew, (float*)d_out, E);
    }
}

// Round 18
// 200.019 us; speedup vs baseline: 1.1546x; 1.1546x over previous
//
#include <hip/hip_runtime.h>

#define D 128
#define BP_LOG 7           // partition bucket = 128 rows (nb=782: long runs)
#define ROWS_H 64          // sortspmm half-bucket = 64 rows
#define MAX_NB 1024        // partition buckets; supports N <= 131072
#define GEMM_GRID 784      // gemm block-range: 1563 tiles -> 2/block
#define CHUNK_LOG 12       // partition chunk = 4096 edges
#define CAP 2560           // LDS record capacity per half (mean 2047, +11 sigma)
#define BCAP 4864          // se1 slots per bucket (mean 4092, +12 sigma)
#define OCAP 32768         // global overflow record capacity

typedef short bf16x8 __attribute__((ext_vector_type(8)));
typedef float f32x4  __attribute__((ext_vector_type(4)));

// round-to-nearest-even float -> bf16 bits
static __device__ __forceinline__ unsigned short f2bf(float f) {
    unsigned u = __float_as_uint(f);
    u += 0x7FFFu + ((u >> 16) & 1u);
    return (unsigned short)(u >> 16);
}

// ---------------------------------------------------------------------------
// Wt[mat][n][k] = bf16(Wmat[k][n]); zeroes bcnt[nb] and ocur (no memset,
// no bhist/bscan dispatches needed with fixed-capacity buckets).
// ---------------------------------------------------------------------------
__global__ __launch_bounds__(256) void wconv_kernel(
    const float* __restrict__ W, const float* __restrict__ Ws,
    short* __restrict__ Wt, int* __restrict__ bcnt, int nb)
{
    const int idx = blockIdx.x * 256 + threadIdx.x;
    if (idx < 2 * D * D) {
        const int mat = idx >> 14;
        const int rem = idx & (D * D - 1);
        const int n = rem >> 7, k = rem & (D - 1);
        const float* src = mat ? Ws : W;
        Wt[idx] = (short)f2bf(src[k * D + n]);
    }
    if (idx <= nb) bcnt[idx] = 0;      // bcnt[0..nb-1] and ocur = bcnt[nb]
}

// ---------------------------------------------------------------------------
// Fused: blocks [0, GEMM_GRID) = MFMA dual GEMM; the rest = edge partition
// into fixed-capacity 128-row buckets (se1[bkt*BCAP + slot]); slot base from
// atomicAdd(&bcnt[bkt], cnt) -- no prefix scan required. Overflow (> BCAP)
// spills to the global int4 list ovf[] via ocur.
// GEMM: waves 0-1: s1b = bf16(x@W); waves 2-3: skipb = bf16(x@Ws + b).
// Record: ((row & 127) << 20) | col, weight bits.
// ---------------------------------------------------------------------------
__global__ __launch_bounds__(256) void gemm_part_kernel(
    const float* __restrict__ x, const short* __restrict__ Wt,
    const float* __restrict__ b, unsigned short* __restrict__ s1b,
    unsigned short* __restrict__ skipb, int N,
    const int* __restrict__ rows, const int* __restrict__ cols,
    const float* __restrict__ ew, int* __restrict__ bcnt,
    int2* __restrict__ se1, int4* __restrict__ ovf, int E, int nb)
{
    __shared__ short sx[64 * D];   // 16 KiB; partition branch aliases as int[]

    const int t = threadIdx.x;

    if (blockIdx.x >= GEMM_GRID) {
        // ---------------- partition branch ----------------
        int* h = (int*)sx;
        int* ocur = &bcnt[nb];
        const int nbl = gridDim.x - GEMM_GRID;
        const int nchunks = (E + (1 << CHUNK_LOG) - 1) >> CHUNK_LOG;

        for (int c = blockIdx.x - GEMM_GRID; c < nchunks; c += nbl) {
            const int ebeg = c << CHUNK_LOG;
            const int eend = min(ebeg + (1 << CHUNK_LOG), E);

            for (int i = t; i < nb; i += 256) h[i] = 0;
            __syncthreads();

            for (int e = ebeg + t; e < eend; e += 256)
                atomicAdd(&h[rows[e] >> BP_LOG], 1);
            __syncthreads();

            for (int i = t; i < nb; i += 256) {
                const int cnt = h[i];
                h[i] = cnt ? atomicAdd(&bcnt[i], cnt) : 0;
            }
            __syncthreads();

            for (int e = ebeg + t; e < eend; e += 256) {
                const int r    = rows[e];
                const int bkt  = r >> BP_LOG;
                const int slot = atomicAdd(&h[bkt], 1);
                if (slot < BCAP) {
                    se1[(size_t)bkt * BCAP + slot] =
                        make_int2(((r & 127) << 20) | cols[e],
                                  __float_as_int(ew[e]));
                } else {
                    const int oi = atomicAdd(ocur, 1);
                    if (oi < OCAP)
                        ovf[oi] = make_int4(r, cols[e],
                                            __float_as_int(ew[e]), 0);
                }
            }
            __syncthreads();
        }
        return;
    }

    // ---------------- MFMA dual GEMM branch ----------------
    const int lane = t & 63;
    const int w    = t >> 6;

    const int bmat = w >> 1;
    const int bn0  = (w & 1) * 64 + (lane & 15);
    const int bk0  = (lane >> 4) * 8;
    bf16x8 Bf[4][4];   // [nf][ks]
#pragma unroll
    for (int nf = 0; nf < 4; ++nf)
#pragma unroll
        for (int ks = 0; ks < 4; ++ks)
            Bf[nf][ks] = *(const bf16x8*)&Wt[
                ((size_t)bmat * D + bn0 + nf * 16) * D + ks * 32 + bk0];

    float bias[4];
#pragma unroll
    for (int nf = 0; nf < 4; ++nf)
        bias[nf] = (w >= 2) ? b[(w - 2) * 64 + nf * 16 + (lane & 15)] : 0.f;

    const int ntiles = (N + 63) >> 6;
    const int trow = t >> 2;
    const int tk   = (t & 3) * 4;

    for (int rt = blockIdx.x; rt < ntiles; rt += GEMM_GRID) {
        const int r0 = rt << 6;
        __syncthreads();

        const int grow = min(r0 + trow, N - 1);
        const float* xrow = &x[(size_t)grow * D];
#pragma unroll
        for (int i = 0; i < 8; ++i) {
            const int k = tk + i * 16;
            const float4 v = *(const float4*)&xrow[k];
            const unsigned lo = (unsigned)f2bf(v.x) | ((unsigned)f2bf(v.y) << 16);
            const unsigned hi = (unsigned)f2bf(v.z) | ((unsigned)f2bf(v.w) << 16);
            unsigned byte = trow * 256 + k * 2;
            byte ^= (unsigned)((trow & 7) << 4);
            *(uint2*)((char*)sx + byte) = make_uint2(lo, hi);
        }
        __syncthreads();

        f32x4 acc[4][4];
#pragma unroll
        for (int mf = 0; mf < 4; ++mf)
#pragma unroll
            for (int nf = 0; nf < 4; ++nf)
                acc[mf][nf] = (f32x4){0.f, 0.f, 0.f, 0.f};

#pragma unroll
        for (int ks = 0; ks < 4; ++ks) {
            bf16x8 Af[4];
#pragma unroll
            for (int mf = 0; mf < 4; ++mf) {
                const int row = mf * 16 + (lane & 15);
                unsigned byte = row * 256 + (ks * 32 + bk0) * 2;
                byte ^= (unsigned)((row & 7) << 4);
                Af[mf] = *(const bf16x8*)((const char*)sx + byte);
            }
#pragma unroll
            for (int mf = 0; mf < 4; ++mf)
#pragma unroll
                for (int nf = 0; nf < 4; ++nf)
                    acc[mf][nf] = __builtin_amdgcn_mfma_f32_16x16x32_bf16(
                        Af[mf], Bf[nf][ks], acc[mf][nf], 0, 0, 0);
        }

#pragma unroll
        for (int mf = 0; mf < 4; ++mf) {
#pragma unroll
            for (int i = 0; i < 4; ++i) {
                const int row = r0 + mf * 16 + (lane >> 4) * 4 + i;
                if (row < N) {
                    if (w < 2) {
#pragma unroll
                        for (int nf = 0; nf < 4; ++nf) {
                            const int col = w * 64 + nf * 16 + (lane & 15);
                            s1b[(size_t)row * D + col] = f2bf(acc[mf][nf][i]);
                        }
                    } else {
#pragma unroll
                        for (int nf = 0; nf < 4; ++nf) {
                            const int col = (w - 2) * 64 + nf * 16 + (lane & 15);
                            skipb[(size_t)row * D + col] =
                                f2bf(acc[mf][nf][i] + bias[nf]);
                        }
                    }
                }
            }
        }
    }
}

// ---------------------------------------------------------------------------
// Fused sort + SpMM, single global scan + 8-deep gather MLP (r16 structure,
// proven at the fill-rate plateau; 16-deep regressed, r17).
// Block (512 thr) = one 64-row half of a 128-row fixed-capacity bucket.
// After the pure out-write, processes the (normally empty) overflow list:
// filter by (bucket, half) -- rows are block-exclusive, atomics safe.
// ---------------------------------------------------------------------------
__global__ __launch_bounds__(512) void sortspmm_kernel(
    const unsigned short* __restrict__ s1b,
    const unsigned short* __restrict__ skipb,
    const int* __restrict__ bcnt, const int2* __restrict__ se1,
    const int4* __restrict__ ovf, float* __restrict__ out, int N, int nb)
{
    __shared__ long long recs[CAP];          // 20 KiB, append order
    __shared__ unsigned short perm[CAP];     // 5 KiB, row-sorted -> append idx
    __shared__ int rpos[ROWS_H];             // row start
    __shared__ int rcur[ROWS_H];             // counter / cursor (final = end)
    __shared__ int nstage;

    const int t    = threadIdx.x;
    const int lane = t & 63;
    const int wv   = t >> 6;            // 0..7
    const int sb   = blockIdx.x >> 1;   // bucket
    const int hh   = blockIdx.x & 1;    // half
    const int r0   = (sb << BP_LOG) + (hh << 6);
    const int j    = lane * 2;

    const int beg  = sb * BCAP;
    const int end  = beg + min(bcnt[sb], BCAP);
    const long long* seq = (const long long*)se1;

    if (t < ROWS_H) rcur[t] = 0;
    if (t == 0) nstage = 0;
    __syncthreads();

    // single scan: stage this half's records (unsorted, wave-aggregated)
    for (int e = beg + t; e < end; e += 512) {
        const long long rec = seq[e];
        const int rl = (int)((unsigned)rec >> 20);
        const bool m = ((rl >> 6) == hh);
        const unsigned long long bal = __ballot(m);
        if (bal) {
            const int leader = (int)__ffsll((long long)bal) - 1;
            int base = 0;
            if (lane == leader) base = atomicAdd(&nstage, __popcll(bal));
            base = __shfl(base, leader, 64);
            if (m) {
                const int slot = base +
                    (int)__popcll(bal & ((1ull << lane) - 1ull));
                if (slot < CAP) recs[slot] = rec;
            }
        }
    }
    __syncthreads();
    const int hcnt = nstage;

    if (hcnt <= CAP) {
        // LDS-local: count rows
        for (int i = t; i < hcnt; i += 512)
            atomicAdd(&rcur[(int)((unsigned)recs[i] >> 20) & 63], 1);
        __syncthreads();

        // wave-0 shuffle scan over the 64 counts -> exclusive starts
        if (t < ROWS_H) {
            const int v = rcur[t];
            int sc = v;
#pragma unroll
            for (int o = 1; o < 64; o <<= 1) {
                const int u = __shfl_up(sc, o, 64);
                if (lane >= o) sc += u;
            }
            rpos[t] = sc - v;
            rcur[t] = sc - v;
        }
        __syncthreads();

        // LDS-local: build 16-bit permutation (row-sorted -> append index)
        for (int i = t; i < hcnt; i += 512) {
            const int rl = (int)((unsigned)recs[i] >> 20) & 63;
            perm[atomicAdd(&rcur[rl], 1)] = (unsigned short)i;
        }
        __syncthreads();

        // gather: wave per row (8 rows per wave), 8-deep MLP
        for (int i2 = 0; i2 < 8; ++i2) {
            const int rr = wv * 8 + i2;
            const int r  = r0 + rr;
            if (r >= N) break;
            int p        = rpos[rr];
            const int pe = rcur[rr];    // final cursor == row end

            float2 acc = make_float2(0.f, 0.f);
            for (; p + 8 <= pe; p += 8) {
                int idx[8];
#pragma unroll
                for (int k = 0; k < 8; ++k) idx[k] = perm[p + k];
                long long ed[8];
#pragma unroll
                for (int k = 0; k < 8; ++k) ed[k] = recs[idx[k]];
                unsigned pk[8];
#pragma unroll
                for (int k = 0; k < 8; ++k)
                    pk[k] = *(const unsigned*)&s1b[
                        (size_t)((unsigned)ed[k] & 0xFFFFFu) * D + j];
#pragma unroll
                for (int k = 0; k < 8; ++k) {
                    const float w = __int_as_float((int)(ed[k] >> 32));
                    acc.x = fmaf(w, __uint_as_float(pk[k] << 16), acc.x);
                    acc.y = fmaf(w, __uint_as_float(pk[k] & 0xFFFF0000u), acc.y);
                }
            }
            for (; p < pe; ++p) {
                const long long ed = recs[perm[p]];
                const unsigned pk = *(const unsigned*)&s1b[
                    (size_t)((unsigned)ed & 0xFFFFFu) * D + j];
                const float w = __int_as_float((int)(ed >> 32));
                acc.x = fmaf(w, __uint_as_float(pk << 16), acc.x);
                acc.y = fmaf(w, __uint_as_float(pk & 0xFFFF0000u), acc.y);
            }

            const unsigned sk = *(const unsigned*)&skipb[(size_t)r * D + j];
            float2 o;
            o.x = acc.x + __uint_as_float(sk << 16);
            o.y = acc.y + __uint_as_float(sk & 0xFFFF0000u);
            *(float2*)&out[(size_t)r * D + j] = o;
        }
    } else {
        // half-overflow fallback: skip init + filtered wave-per-edge atomics
        const int nr = min(ROWS_H, N - r0);
        for (int idx = t; idx < nr * 64; idx += 512) {
            const int rr = idx >> 6;
            const int cc = (idx & 63) * 2;
            const unsigned sk = *(const unsigned*)&skipb[(size_t)(r0 + rr) * D + cc];
            *(float2*)&out[(size_t)(r0 + rr) * D + cc] =
                make_float2(__uint_as_float(sk << 16),
                            __uint_as_float(sk & 0xFFFF0000u));
        }
        __syncthreads();

        for (int e = beg + wv; e < end; e += 8) {
            const long long ed = seq[e];
            const unsigned key = (unsigned)ed;
            const int rl = (int)(key >> 20);
            if ((rl >> 6) != hh) continue;
            const float w = __int_as_float((int)(ed >> 32));
            const unsigned pk = *(const unsigned*)&s1b[
                (size_t)(key & 0xFFFFFu) * D + j];
            float* op = &out[(size_t)(r0 + (rl & 63)) * D + j];
            unsafeAtomicAdd(op,     w * __uint_as_float(pk << 16));
            unsafeAtomicAdd(op + 1, w * __uint_as_float(pk & 0xFFFF0000u));
        }
    }

    // global bucket-overflow records (normally zero): rows are this block's.
    __syncthreads();
    const int novf = min(bcnt[nb], OCAP);
    for (int i = t >> 6; i < novf; i += 8) {     // wave-per-record
        const int4 rec = ovf[i];
        if ((rec.x >> BP_LOG) != sb || (((rec.x >> 6) & 1) != hh)) continue;
        const float w = __int_as_float(rec.z);
        const unsigned pk = *(const unsigned*)&s1b[(size_t)rec.y * D + j];
        float* op = &out[(size_t)rec.x * D + j];
        unsafeAtomicAdd(op,     w * __uint_as_float(pk << 16));
        unsafeAtomicAdd(op + 1, w * __uint_as_float(pk & 0xFFFF0000u));
    }
}

// ---------------------------------------------------------------------------
// Fallback vector dual GEMM (ws too small): fp32 math, bf16 s1 store,
// fp32 out init (used with the atomic spmm_edges fallback).
// ---------------------------------------------------------------------------
__global__ __launch_bounds__(512) void dual_gemm_fb_kernel(
    const float* __restrict__ x, const float* __restrict__ W,
    const float* __restrict__ Ws, const float* __restrict__ b,
    unsigned short* __restrict__ s1b, float* __restrict__ out, int N)
{
    __shared__ float sW[D * D];
    __shared__ float sWs[D * D];

    const int t = threadIdx.x;
    for (int i = t * 4; i < D * D; i += 512 * 4) {
        *(float4*)&sW[i]  = *(const float4*)&W[i];
        *(float4*)&sWs[i] = *(const float4*)&Ws[i];
    }
    __syncthreads();

    const int lane   = t & 63;
    const int wave   = blockIdx.x * 8 + (t >> 6);
    const int nwaves = gridDim.x * 8;
    const int j      = lane * 2;
    const float2 bb  = *(const float2*)&b[j];

    for (int r0 = wave * 4; r0 < N; r0 += nwaves * 4) {
        float2 xr[4];
#pragma unroll
        for (int r = 0; r < 4; ++r)
            xr[r] = *(const float2*)&x[(size_t)(r0 + r) * D + j];

        float2 a1[4], a2[4];
#pragma unroll
        for (int r = 0; r < 4; ++r) {
            a1[r] = make_float2(0.f, 0.f);
            a2[r] = make_float2(0.f, 0.f);
        }

#pragma unroll 8
        for (int k = 0; k < D; ++k) {
            const float2 wk  = *(const float2*)&sW[k * D + j];
            const float2 wsk = *(const float2*)&sWs[k * D + j];
#pragma unroll
            for (int r = 0; r < 4; ++r) {
                const float xv = __shfl((k & 1) ? xr[r].y : xr[r].x, k >> 1, 64);
                a1[r].x = fmaf(xv, wk.x,  a1[r].x);
                a1[r].y = fmaf(xv, wk.y,  a1[r].y);
                a2[r].x = fmaf(xv, wsk.x, a2[r].x);
                a2[r].y = fmaf(xv, wsk.y, a2[r].y);
            }
        }

#pragma unroll
        for (int r = 0; r < 4; ++r) {
            const unsigned pk = (unsigned)f2bf(a1[r].x) |
                                ((unsigned)f2bf(a1[r].y) << 16);
            *(unsigned*)&s1b[(size_t)(r0 + r) * D + j] = pk;
            *(float2*)&out[(size_t)(r0 + r) * D + j] =
                make_float2(a2[r].x + bb.x, a2[r].y + bb.y);
        }
    }
}

// ---------------------------------------------------------------------------
// Fallback: edge-parallel atomic scatter (bf16 s1).
// ---------------------------------------------------------------------------
__global__ __launch_bounds__(256) void spmm_edges_kernel(
    const unsigned short* __restrict__ s1b, const int* __restrict__ rows,
    const int* __restrict__ cols, const float* __restrict__ ew,
    float* __restrict__ out, int E)
{
    const int lane = threadIdx.x & 63;
    const int wave = blockIdx.x * (blockDim.x >> 6) + (threadIdx.x >> 6);
    const int nw   = gridDim.x * (blockDim.x >> 6);
    const int j    = lane * 2;

    const int epw   = (E + nw - 1) / nw;
    const int e_beg = wave * epw;
    const int e_end = min(e_beg + epw, E);

    for (int e = e_beg; e < e_end; ++e) {
        const int   r = rows[e];
        const int   c = cols[e];
        const float w = ew[e];
        const unsigned p = *(const unsigned*)&s1b[(size_t)c * D + j];
        float* o = &out[(size_t)r * D + j];
        unsafeAtomicAdd(o,     w * __uint_as_float(p << 16));
        unsafeAtomicAdd(o + 1, w * __uint_as_float(p & 0xFFFF0000u));
    }
}

// ---------------------------------------------------------------------------
extern "C" void kernel_launch(void* const* d_in, const int* in_sizes, int n_in,
                              void* d_out, int out_size, void* d_ws, size_t ws_size,
                              hipStream_t stream) {
    const float* x    = (const float*)d_in[0];
    const int*   rows = (const int*)  d_in[1];
    const int*   cols = (const int*)  d_in[2];
    const float* ew   = (const float*)d_in[3];
    const float* W    = (const float*)d_in[4];
    const float* Ws   = (const float*)d_in[5];
    const float* b    = (const float*)d_in[6];
    float*       out  = (float*)d_out;

    const int N  = in_sizes[0] / D;
    const int E  = in_sizes[1];
    const int nb = (N + 127) >> BP_LOG;   // 128-row buckets

    // Workspace: s1b | skipb | Wt | bcnt[nb]+ocur | pad | ovf OCAP int4 |
    //            se1 nb*BCAP int2
    const size_t s1_bytes   = ((size_t)N * D * 2 + 15) & ~(size_t)15;
    const size_t skip_bytes = s1_bytes;
    const size_t wt_bytes   = (size_t)2 * D * D * 2;
    const size_t int_bytes  = (((size_t)(nb + 1)) * 4 + 15) & ~(size_t)15;
    const size_t ovf_bytes  = (size_t)OCAP * 16;
    const size_t se1_bytes  = (size_t)nb * BCAP * 8;
    const size_t need       = s1_bytes + skip_bytes + wt_bytes + int_bytes
                              + ovf_bytes + se1_bytes;

    unsigned short* s1b = (unsigned short*)d_ws;

    if (ws_size >= need && nb <= MAX_NB) {
        unsigned short* skipb = (unsigned short*)((char*)d_ws + s1_bytes);
        short* Wt   = (short*)((char*)d_ws + s1_bytes + skip_bytes);
        int*   bcnt = (int*)((char*)d_ws + s1_bytes + skip_bytes + wt_bytes);
        int4*  ovf  = (int4*)((char*)d_ws + s1_bytes + skip_bytes + wt_bytes
                              + int_bytes);
        int2*  se1  = (int2*)((char*)d_ws + s1_bytes + skip_bytes + wt_bytes
                              + int_bytes + ovf_bytes);

        wconv_kernel<<<(2 * D * D + 255) / 256, 256, 0, stream>>>(W, Ws, Wt, bcnt, nb);

        const int nchunks = (E + (1 << CHUNK_LOG) - 1) >> CHUNK_LOG;
        const int part_blocks = min(nchunks, 1024);
        gemm_part_kernel<<<GEMM_GRID + part_blocks, 256, 0, stream>>>(
            x, Wt, b, s1b, skipb, N, rows, cols, ew, bcnt, se1, ovf, E, nb);

        sortspmm_kernel<<<nb * 2, 512, 0, stream>>>(
            s1b, skipb, bcnt, se1, ovf, out, N, nb);
    } else {
        dual_gemm_fb_kernel<<<768, 512, 0, stream>>>(x, W, Ws, b, s1b, (float*)d_out, N);
        spmm_edges_kernel<<<2048, 256, 0, stream>>>(s1b, rows, cols, ew, (float*)d_out, E);
    }
}